// Round 9
// baseline (375.171 us; speedup 1.0000x reference)
//
#include <hip/hip_runtime.h>
#include <stdint.h>

#define NB 4
#define NS 2048
#define NHID 768
#define NNH 12
#define NHD 64
#define NBH 48
#define LOG2E 1.4426950408889634f

typedef __attribute__((ext_vector_type(8))) __bf16 bf16x8;
typedef __attribute__((ext_vector_type(4))) float f32x4;
typedef __attribute__((ext_vector_type(16))) float f32x16;

static __device__ __forceinline__ unsigned short f2bf(float f) {
  union { float f; uint32_t u; } v; v.f = f;
  uint32_t r = (v.u + 0x7FFFu + ((v.u >> 16) & 1u)) >> 16;  // RNE
  return (unsigned short)r;
}

static __device__ __forceinline__ unsigned int cvtpk(float lo, float hi) {
  unsigned int r;
  asm("v_cvt_pk_bf16_f32 %0, %1, %2" : "=v"(r) : "v"(lo), "v"(hi));
  return r;
}

#define GLDS(src, dst) __builtin_amdgcn_global_load_lds( \
    (const __attribute__((address_space(1))) void*)(src), \
    (__attribute__((address_space(3))) void*)(dst), 16, 0, 0)

// ---------------- kernel 0: fp32 -> bf16 (X and W concat) ----------------
__global__ void cvt_kernel(const float* __restrict__ X,
                           const float* __restrict__ Wq,
                           const float* __restrict__ Wk,
                           const float* __restrict__ Wv,
                           unsigned short* __restrict__ xb,
                           unsigned short* __restrict__ wb) {
  const int NX = NB * NS * NHID;   // 6291456
  const int NW = NHID * NHID;      // 589824
  int i = (blockIdx.x * blockDim.x + threadIdx.x) * 4;
  if (i < NX) {
    const float4 v = *(const float4*)(X + i);
    ushort4 o;
    o.x = f2bf(v.x); o.y = f2bf(v.y); o.z = f2bf(v.z); o.w = f2bf(v.w);
    *(ushort4*)(xb + i) = o;
  } else {
    int j = i - NX;
    const float* W; int jj;
    if (j < NW)          { W = Wq; jj = j; }
    else if (j < 2 * NW) { W = Wk; jj = j - NW; }
    else                 { W = Wv; jj = j - 2 * NW; }
    const float4 v = *(const float4*)(W + jj);
    ushort4 o;
    o.x = f2bf(v.x); o.y = f2bf(v.y); o.z = f2bf(v.z); o.w = f2bf(v.w);
    *(ushort4*)(wb + j) = o;
  }
}

// ---------------- kernel 1: fused QKV projection GEMM ----------------
// 128x128 tile, BK=64, 4 waves, global_load_lds(16B) into XOR-swizzled LDS.
__global__ void qkv_gemm(const unsigned short* __restrict__ xb,   // [8192][768] bf16
                         const unsigned short* __restrict__ wb,   // [3][768][768] bf16
                         const float* __restrict__ bq,
                         const float* __restrict__ bk,
                         const float* __restrict__ bv,
                         unsigned short* __restrict__ qw,   // [48][2048][64] (scaled 0.125*log2e)
                         unsigned short* __restrict__ kw,   // [48][2048][64]
                         unsigned short* __restrict__ vw) { // [48][64][2048] (transposed)
  __shared__ unsigned char As[128 * 128];   // [row][128B K-slab], swizzled
  __shared__ unsigned char Bs[128 * 128];
  const int tid = threadIdx.x;
  const int lane = tid & 63, wid = tid >> 6;
  const int l15 = lane & 15, l4 = lane >> 4;
  const int wr = wid >> 1, wc = wid & 1;
  const int mblock = blockIdx.x;   // 0..63
  const int ct = blockIdx.y;       // 0..17
  const int which = ct / 6, ctn = ct % 6;
  const int mbase = mblock * 128, nbase = ctn * 128;
  const unsigned short* Wb = wb + (size_t)which * NHID * NHID;

  const int srow = lane >> 3;                               // 0..7
  const int swz16 = ((lane & 7) * 16) ^ (srow << 4);        // < 128
  const unsigned char* agp = (const unsigned char*)xb + (size_t)mbase * (NHID * 2);
  const unsigned char* bgp = (const unsigned char*)Wb + (size_t)nbase * (NHID * 2);

  f32x4 acc[4][4];
  const f32x4 fzero = {0.f, 0.f, 0.f, 0.f};
#pragma unroll
  for (int mi = 0; mi < 4; ++mi)
#pragma unroll
    for (int ni = 0; ni < 4; ++ni) acc[mi][ni] = fzero;

  const int swzr = (l15 & 7) << 4;   // read-side XOR (row&7 == l15&7)

  for (int kt = 0; kt < 12; ++kt) {
    __syncthreads();
#pragma unroll
    for (int g = 0; g < 4; ++g) {
      int row = wid * 32 + g * 8 + srow;
      GLDS(agp + (size_t)row * (NHID * 2) + kt * 128 + swz16,
           As + (wid * 32 + g * 8) * 128);
      GLDS(bgp + (size_t)row * (NHID * 2) + kt * 128 + swz16,
           Bs + (wid * 32 + g * 8) * 128);
    }
    __syncthreads();   // vmcnt drained by barrier
#pragma unroll
    for (int ks = 0; ks < 2; ++ks) {
      bf16x8 af[4], bf[4];
#pragma unroll
      for (int mi = 0; mi < 4; ++mi)
        af[mi] = *(const bf16x8*)(As + (wr * 64 + mi * 16 + l15) * 128 +
                                  ((ks * 64 + l4 * 16) ^ swzr));
#pragma unroll
      for (int ni = 0; ni < 4; ++ni)
        bf[ni] = *(const bf16x8*)(Bs + (wc * 64 + ni * 16 + l15) * 128 +
                                  ((ks * 64 + l4 * 16) ^ swzr));
#pragma unroll
      for (int mi = 0; mi < 4; ++mi)
#pragma unroll
        for (int ni = 0; ni < 4; ++ni)
          acc[mi][ni] = __builtin_amdgcn_mfma_f32_16x16x32_bf16(af[mi], bf[ni], acc[mi][ni], 0, 0, 0);
    }
  }

  const float* bias = (which == 0) ? bq : (which == 1) ? bk : bv;
#pragma unroll
  for (int mi = 0; mi < 4; ++mi) {
    int row0 = mbase + wr * 64 + mi * 16 + l4 * 4;
    int b = row0 >> 11, s0 = row0 & 2047;
#pragma unroll
    for (int ni = 0; ni < 4; ++ni) {
      int col = nbase + wc * 64 + ni * 16 + l15;   // 0..767
      float bv_ = bias[col];
      int h = col >> 6, d = col & 63;
      if (which == 2) {
        ushort4 o;
        o.x = f2bf(acc[mi][ni][0] + bv_);
        o.y = f2bf(acc[mi][ni][1] + bv_);
        o.z = f2bf(acc[mi][ni][2] + bv_);
        o.w = f2bf(acc[mi][ni][3] + bv_);
        *(ushort4*)(vw + ((size_t)(b * NNH + h) * NHD + d) * NS + s0) = o;
      } else {
        unsigned short* dst = (which == 0) ? qw : kw;
        // Q carries 1/sqrt(64) * log2e so scores come out in log2 units
        float sc = (which == 0) ? 0.125f * LOG2E : 1.0f;
#pragma unroll
        for (int r = 0; r < 4; ++r) {
          float val = (acc[mi][ni][r] + bv_) * sc;
          dst[((size_t)(b * NNH + h) * NS + (s0 + r)) * NHD + d] = f2bf(val);
        }
      }
    }
  }
}

// ---------------- kernel 2: flash attention, 8-wave in-block split-KV ----------------
// grid 768 (XCD-remapped), 512 threads = 2 groups x 4 waves. Group g handles
// keys [g*1024,(g+1)*1024); both cover the same 128 q-rows.
// LDS per group: K double-buffer (2x8KB) + V single buffer (8KB) = 24KB
// -> 48KB/block -> 3 blocks/CU co-resident (768 = 3*256: zero tail).
// V(t)'s staging latency hides under the QK^T+softmax phase; mid-tile sync
// makes it visible, end-of-tile sync frees the V buffer.
__global__ __launch_bounds__(512, 6)
void attn_kernel(const unsigned short* __restrict__ qw,
                 const unsigned short* __restrict__ kw,
                 const unsigned short* __restrict__ vw,
                 const float* __restrict__ mask,
                 float* __restrict__ out) {
  __shared__ unsigned char lds[49152];  // [g][Kbuf0 8K | Kbuf1 8K | V 8K]; reused for merge

  const int tid = threadIdx.x;
  const int lane = tid & 63, wid = tid >> 6;       // wid 0..7
  const int g = wid >> 2, wg = wid & 3;            // group, wave-in-group
  const int l31 = lane & 31, hi = lane >> 5;
  const int r_ = blockIdx.x;           // 0..767
  const int j_ = r_ >> 3, xcd = r_ & 7;
  const int bh = xcd * 6 + (j_ % 6);   // bh-major per XCD
  const int qb = j_ / 6;               // 0..15
  const int b = bh / NNH, h = bh % NNH;
  const size_t bh_off = (size_t)bh * NS * NHD;
  const int qbase = qb * 128 + wg * 32;
  const int qlocal = wg * 32 + l31;    // 0..127 (softmax-domain q within block)

  // hoist Q B-fragments: Q[q = qbase+l31][d = dk*16 + hi*8 + j]
  bf16x8 qf[4];
#pragma unroll
  for (int dk = 0; dk < 4; ++dk)
    qf[dk] = *(const bf16x8*)(qw + bh_off + (size_t)(qbase + l31) * NHD + dk * 16 + hi * 8);

  // staging: per-lane pre-swizzled global offsets (LDS dest is linear)
  const int swz16 = ((lane & 7) * 16) ^ (((lane >> 3) & 7) << 4);
  const unsigned char* kgp = (const unsigned char*)(kw + bh_off);
  const unsigned char* vgp = (const unsigned char*)(vw + bh_off);
  const int kst = (lane >> 3) * 128 + swz16;                 // within K row-block
  const size_t vst = (size_t)(lane >> 3) * (NS * 2) + swz16; // V^T rows stride 4096B

  // ds_read col offsets (swizzled); row&7 == l31&7 for all our reads
  const int swzr = (l31 & 7) << 4;
  int colA[4];
#pragma unroll
  for (int i = 0; i < 4; ++i) colA[i] = (i * 32 + hi * 16) ^ swzr;

  const float* maskp = mask + b * NS + g * 1024;
  unsigned char* const gbase = lds + g * 24576;
  unsigned char* const vbuf = gbase + 16384;

  f32x16 oacc[2];
#pragma unroll
  for (int db = 0; db < 2; ++db)
#pragma unroll
    for (int e = 0; e < 16; ++e) oacc[db][e] = 0.f;
  float mrun = 8.0f;   // static log2-domain exponent bias
  float lrun = 0.f;    // per-lane PARTIAL (own 32 keys); partner-combined at end

#define STAGE_K(t_, buf_) do { \
    size_t kb0 = (size_t)(g * 1024 + (t_) * 64); \
    unsigned char* kd = gbase + (buf_) * 8192; \
    GLDS(kgp + kb0 * 128 + (wg * 2 + 0) * 1024 + kst, kd + (wg * 2 + 0) * 1024); \
    GLDS(kgp + kb0 * 128 + (wg * 2 + 1) * 1024 + kst, kd + (wg * 2 + 1) * 1024); \
  } while (0)
#define STAGE_V(t_) do { \
    size_t kb0 = (size_t)(g * 1024 + (t_) * 64); \
    GLDS(vgp + (size_t)(wg * 2 + 0) * 8 * (NS * 2) + kb0 * 2 + vst, vbuf + (wg * 2 + 0) * 1024); \
    GLDS(vgp + (size_t)(wg * 2 + 1) * 8 * (NS * 2) + kb0 * 2 + vst, vbuf + (wg * 2 + 1) * 1024); \
  } while (0)

  STAGE_K(0, 0);
  __syncthreads();   // K(0) landed + visible

  for (int t = 0; t < 16; ++t) {
    // V(t) overwrite is safe: previous end-of-tile barrier ensured PV(t-1) done.
    STAGE_V(t);
    if (t + 1 < 16) STAGE_K(t + 1, (t + 1) & 1);

    const unsigned char* klds = gbase + (t & 1) * 8192;

    // S^T accumulators, C-init = mask*log2e - mrun (fused: one FMA per element)
    f32x16 acc2[2];
#pragma unroll
    for (int kb = 0; kb < 2; ++kb)
#pragma unroll
      for (int c = 0; c < 4; ++c) {
        float4 mv = *(const float4*)(maskp + t * 64 + kb * 32 + c * 8 + hi * 4);
        acc2[kb][c * 4 + 0] = fmaf(mv.x, LOG2E, -mrun);
        acc2[kb][c * 4 + 1] = fmaf(mv.y, LOG2E, -mrun);
        acc2[kb][c * 4 + 2] = fmaf(mv.z, LOG2E, -mrun);
        acc2[kb][c * 4 + 3] = fmaf(mv.w, LOG2E, -mrun);
      }

    // QK^T (swapped): acc2[kb][reg] = S[q=l31][key = kb*32 + (reg&3)+8*(reg>>2)+4*hi]
    __builtin_amdgcn_s_setprio(1);
#pragma unroll
    for (int kb = 0; kb < 2; ++kb)
#pragma unroll
      for (int dk = 0; dk < 4; ++dk) {
        bf16x8 kf = *(const bf16x8*)(klds + (kb * 32 + l31) * 128 + colA[dk]);
        acc2[kb] = __builtin_amdgcn_mfma_f32_32x32x16_bf16(kf, qf[dk], acc2[kb], 0, 0, 0);
      }
    __builtin_amdgcn_s_setprio(0);

    // p = 2^(S + maskL - mrun) directly (bias already folded into C-init)
#pragma unroll
    for (int kb = 0; kb < 2; ++kb)
#pragma unroll
      for (int e = 0; e < 16; ++e)
        acc2[kb][e] = __builtin_amdgcn_exp2f(acc2[kb][e]);
    float s8[8];
#pragma unroll
    for (int e = 0; e < 8; ++e)
      s8[e] = (acc2[0][e] + acc2[0][e + 8]) + (acc2[1][e] + acc2[1][e + 8]);
    float rsum = ((s8[0] + s8[1]) + (s8[2] + s8[3])) +
                 ((s8[4] + s8[5]) + (s8[6] + s8[7]));

    // cold safety: exact power-of-2 rescale if p's got huge (uniform -> no routing)
    int guard = 0;
    while (!__all(rsum <= 0x1p40f) && ++guard < 4) {
      const float c = 0x1p-64f;
#pragma unroll
      for (int kb = 0; kb < 2; ++kb)
#pragma unroll
        for (int e = 0; e < 16; ++e) acc2[kb][e] *= c;
#pragma unroll
      for (int r = 0; r < 16; ++r) { oacc[0][r] *= c; oacc[1][r] *= c; }
      lrun *= c; rsum *= c; mrun += 64.0f;
    }
    lrun += rsum;

    __syncthreads();   // V(t) (and K(t+1)) drained + visible; staging hid under softmax

    // PV fused per-ks: P->bf16 (cvtpk), partner exchange, MFMA.
    // af[ks][j] = P[q=l31][key = ks*16 + hi*8 + j]
    __builtin_amdgcn_s_setprio(1);
#pragma unroll
    for (int ks = 0; ks < 4; ++ks) {
      const int kb = ks >> 1, cl = (2 * ks) & 3, ch = cl + 1;
      unsigned int wa0 = cvtpk(acc2[kb][cl * 4 + 0], acc2[kb][cl * 4 + 1]);
      unsigned int wa1 = cvtpk(acc2[kb][cl * 4 + 2], acc2[kb][cl * 4 + 3]);
      unsigned int wb0 = cvtpk(acc2[kb][ch * 4 + 0], acc2[kb][ch * 4 + 1]);
      unsigned int wb1 = cvtpk(acc2[kb][ch * 4 + 2], acc2[kb][ch * 4 + 3]);
      unsigned int s0 = hi ? wa0 : wb0;
      unsigned int s1 = hi ? wa1 : wb1;
      unsigned int r0 = __shfl_xor(s0, 32);
      unsigned int r1 = __shfl_xor(s1, 32);
      union { unsigned int u[4]; bf16x8 v; } afu;
      afu.u[0] = hi ? r0 : wa0;
      afu.u[1] = hi ? r1 : wa1;
      afu.u[2] = hi ? wb0 : r0;
      afu.u[3] = hi ? wb1 : r1;
      bf16x8 vf0 = *(const bf16x8*)(vbuf + (0 * 32 + l31) * 128 + colA[ks]);
      bf16x8 vf1 = *(const bf16x8*)(vbuf + (1 * 32 + l31) * 128 + colA[ks]);
      oacc[0] = __builtin_amdgcn_mfma_f32_32x32x16_bf16(afu.v, vf0, oacc[0], 0, 0, 0);
      oacc[1] = __builtin_amdgcn_mfma_f32_32x32x16_bf16(afu.v, vf1, oacc[1], 0, 0, 0);
    }
    __builtin_amdgcn_s_setprio(0);

    __syncthreads();   // PV(t) done by all -> V buffer free for t+1
  }

  // combine partner-lane partial sums once (was per-tile)
  lrun += __shfl_xor(lrun, 32);

  // ---------- two-way flash merge (groups A/B over same q-rows) ----------
  float* fl = (float*)lds;
  // phase 1: publish (m, l) per q; hi==0 lanes write  (post-loop barrier above)
  if (hi == 0) {
    fl[g * 256 + qlocal] = mrun;
    fl[g * 256 + 128 + qlocal] = lrun;
  }
  __syncthreads();
  // phase 2: read other group's stats, compute combined scale
  float mo = fl[(1 - g) * 256 + qlocal];
  float lo_ = fl[(1 - g) * 256 + 128 + qlocal];
  float mstar = fmaxf(mrun, mo);
  float sG = __builtin_amdgcn_exp2f(mrun - mstar);           // own-group scale
  float lstar = lrun * sG + lo_ * __builtin_amdgcn_exp2f(mo - mstar);
  float s_r[16];
#pragma unroll
  for (int r = 0; r < 16; ++r)
    s_r[r] = __shfl(sG, (r & 3) + 8 * (r >> 2) + 4 * hi);
  __syncthreads();                   // stats consumed before O overwrite
  // phase 3: group B writes scaled O to LDS [128 q][64 d] fp32
  if (g == 1) {
#pragma unroll
    for (int reg = 0; reg < 16; ++reg) {
      int qr = wg * 32 + (reg & 3) + 8 * (reg >> 2) + 4 * hi;
      fl[qr * 64 + l31]      = oacc[0][reg] * s_r[reg];
      fl[qr * 64 + 32 + l31] = oacc[1][reg] * s_r[reg];
    }
  }
  __syncthreads();
  // phase 4: group A combines, normalizes, stores fp32 merge-heads layout
  if (g == 0) {
    float invl = 1.0f / lstar;       // softmax domain (q = l31)
#pragma unroll
    for (int reg = 0; reg < 16; ++reg) {
      int q_local = (reg & 3) + 8 * (reg >> 2) + 4 * hi;
      float inv_r = __shfl(invl, q_local);
      int qr = wg * 32 + q_local;
      int q = qb * 128 + qr;
      float o0 = oacc[0][reg] * s_r[reg] + fl[qr * 64 + l31];
      float o1 = oacc[1][reg] * s_r[reg] + fl[qr * 64 + 32 + l31];
      out[((size_t)b * NS + q) * NHID + h * 64 + l31]      = o0 * inv_r;
      out[((size_t)b * NS + q) * NHID + h * 64 + 32 + l31] = o1 * inv_r;
    }
  }
#undef STAGE_K
#undef STAGE_V
}

extern "C" void kernel_launch(void* const* d_in, const int* in_sizes, int n_in,
                              void* d_out, int out_size, void* d_ws, size_t ws_size,
                              hipStream_t stream) {
  const float* X    = (const float*)d_in[0];
  const float* mask = (const float*)d_in[1];
  const float* Wq   = (const float*)d_in[2];
  const float* bq   = (const float*)d_in[3];
  const float* Wk   = (const float*)d_in[4];
  const float* bk   = (const float*)d_in[5];
  const float* Wv   = (const float*)d_in[6];
  const float* bv   = (const float*)d_in[7];
  float* out = (float*)d_out;

  unsigned short* xb = (unsigned short*)d_out;            // scratch, overwritten by attn out
  unsigned short* wb = xb + (size_t)NB * NS * NHID;
  unsigned short* qw = (unsigned short*)d_ws;
  unsigned short* kw = qw + (size_t)NBH * NS * NHD;
  unsigned short* vw = kw + (size_t)NBH * NS * NHD;

  cvt_kernel<<<7872, 256, 0, stream>>>(X, Wq, Wk, Wv, xb, wb);
  qkv_gemm<<<dim3(64, 18), 256, 0, stream>>>(xb, wb, bq, bk, bv, qw, kw, vw);
  attn_kernel<<<768, 512, 0, stream>>>(qw, kw, vw, mask, out);
}

// Round 10
// 132.051 us; speedup vs baseline: 2.8411x; 2.8411x over previous
//
#include <hip/hip_runtime.h>
#include <stdint.h>

#define NB 4
#define NS 2048
#define NHID 768
#define NNH 12
#define NHD 64
#define NBH 48
#define LOG2E 1.4426950408889634f

typedef __attribute__((ext_vector_type(8))) __bf16 bf16x8;
typedef __attribute__((ext_vector_type(4))) float f32x4;
typedef __attribute__((ext_vector_type(16))) float f32x16;

static __device__ __forceinline__ unsigned short f2bf(float f) {
  union { float f; uint32_t u; } v; v.f = f;
  uint32_t r = (v.u + 0x7FFFu + ((v.u >> 16) & 1u)) >> 16;  // RNE
  return (unsigned short)r;
}

static __device__ __forceinline__ unsigned int cvtpk(float lo, float hi) {
  unsigned int r;
  asm("v_cvt_pk_bf16_f32 %0, %1, %2" : "=v"(r) : "v"(lo), "v"(hi));
  return r;
}

#define GLDS(src, dst) __builtin_amdgcn_global_load_lds( \
    (const __attribute__((address_space(1))) void*)(src), \
    (__attribute__((address_space(3))) void*)(dst), 16, 0, 0)

// ---------------- kernel 0: fp32 -> bf16 (X and W concat) ----------------
__global__ void cvt_kernel(const float* __restrict__ X,
                           const float* __restrict__ Wq,
                           const float* __restrict__ Wk,
                           const float* __restrict__ Wv,
                           unsigned short* __restrict__ xb,
                           unsigned short* __restrict__ wb) {
  const int NX = NB * NS * NHID;   // 6291456
  const int NW = NHID * NHID;      // 589824
  int i = (blockIdx.x * blockDim.x + threadIdx.x) * 4;
  if (i < NX) {
    const float4 v = *(const float4*)(X + i);
    ushort4 o;
    o.x = f2bf(v.x); o.y = f2bf(v.y); o.z = f2bf(v.z); o.w = f2bf(v.w);
    *(ushort4*)(xb + i) = o;
  } else {
    int j = i - NX;
    const float* W; int jj;
    if (j < NW)          { W = Wq; jj = j; }
    else if (j < 2 * NW) { W = Wk; jj = j - NW; }
    else                 { W = Wv; jj = j - 2 * NW; }
    const float4 v = *(const float4*)(W + jj);
    ushort4 o;
    o.x = f2bf(v.x); o.y = f2bf(v.y); o.z = f2bf(v.z); o.w = f2bf(v.w);
    *(ushort4*)(wb + j) = o;
  }
}

// ---------------- kernel 1: fused QKV projection GEMM ----------------
// 128x128 tile, BK=64, 4 waves, global_load_lds(16B) into XOR-swizzled LDS.
__global__ void qkv_gemm(const unsigned short* __restrict__ xb,   // [8192][768] bf16
                         const unsigned short* __restrict__ wb,   // [3][768][768] bf16
                         const float* __restrict__ bq,
                         const float* __restrict__ bk,
                         const float* __restrict__ bv,
                         unsigned short* __restrict__ qw,   // [48][2048][64] (scaled 0.125*log2e)
                         unsigned short* __restrict__ kw,   // [48][2048][64]
                         unsigned short* __restrict__ vw) { // [48][64][2048] (transposed)
  __shared__ unsigned char As[128 * 128];   // [row][128B K-slab], swizzled
  __shared__ unsigned char Bs[128 * 128];
  const int tid = threadIdx.x;
  const int lane = tid & 63, wid = tid >> 6;
  const int l15 = lane & 15, l4 = lane >> 4;
  const int wr = wid >> 1, wc = wid & 1;
  const int mblock = blockIdx.x;   // 0..63
  const int ct = blockIdx.y;       // 0..17
  const int which = ct / 6, ctn = ct % 6;
  const int mbase = mblock * 128, nbase = ctn * 128;
  const unsigned short* Wb = wb + (size_t)which * NHID * NHID;

  const int srow = lane >> 3;                               // 0..7
  const int swz16 = ((lane & 7) * 16) ^ (srow << 4);        // < 128
  const unsigned char* agp = (const unsigned char*)xb + (size_t)mbase * (NHID * 2);
  const unsigned char* bgp = (const unsigned char*)Wb + (size_t)nbase * (NHID * 2);

  f32x4 acc[4][4];
  const f32x4 fzero = {0.f, 0.f, 0.f, 0.f};
#pragma unroll
  for (int mi = 0; mi < 4; ++mi)
#pragma unroll
    for (int ni = 0; ni < 4; ++ni) acc[mi][ni] = fzero;

  const int swzr = (l15 & 7) << 4;   // read-side XOR (row&7 == l15&7)

  for (int kt = 0; kt < 12; ++kt) {
    __syncthreads();
#pragma unroll
    for (int g = 0; g < 4; ++g) {
      int row = wid * 32 + g * 8 + srow;
      GLDS(agp + (size_t)row * (NHID * 2) + kt * 128 + swz16,
           As + (wid * 32 + g * 8) * 128);
      GLDS(bgp + (size_t)row * (NHID * 2) + kt * 128 + swz16,
           Bs + (wid * 32 + g * 8) * 128);
    }
    __syncthreads();   // vmcnt drained by barrier
#pragma unroll
    for (int ks = 0; ks < 2; ++ks) {
      bf16x8 af[4], bf[4];
#pragma unroll
      for (int mi = 0; mi < 4; ++mi)
        af[mi] = *(const bf16x8*)(As + (wr * 64 + mi * 16 + l15) * 128 +
                                  ((ks * 64 + l4 * 16) ^ swzr));
#pragma unroll
      for (int ni = 0; ni < 4; ++ni)
        bf[ni] = *(const bf16x8*)(Bs + (wc * 64 + ni * 16 + l15) * 128 +
                                  ((ks * 64 + l4 * 16) ^ swzr));
#pragma unroll
      for (int mi = 0; mi < 4; ++mi)
#pragma unroll
        for (int ni = 0; ni < 4; ++ni)
          acc[mi][ni] = __builtin_amdgcn_mfma_f32_16x16x32_bf16(af[mi], bf[ni], acc[mi][ni], 0, 0, 0);
    }
  }

  const float* bias = (which == 0) ? bq : (which == 1) ? bk : bv;
#pragma unroll
  for (int mi = 0; mi < 4; ++mi) {
    int row0 = mbase + wr * 64 + mi * 16 + l4 * 4;
    int b = row0 >> 11, s0 = row0 & 2047;
#pragma unroll
    for (int ni = 0; ni < 4; ++ni) {
      int col = nbase + wc * 64 + ni * 16 + l15;   // 0..767
      float bv_ = bias[col];
      int h = col >> 6, d = col & 63;
      if (which == 2) {
        ushort4 o;
        o.x = f2bf(acc[mi][ni][0] + bv_);
        o.y = f2bf(acc[mi][ni][1] + bv_);
        o.z = f2bf(acc[mi][ni][2] + bv_);
        o.w = f2bf(acc[mi][ni][3] + bv_);
        *(ushort4*)(vw + ((size_t)(b * NNH + h) * NHD + d) * NS + s0) = o;
      } else {
        unsigned short* dst = (which == 0) ? qw : kw;
        // Q carries 1/sqrt(64) * log2e so scores come out in log2 units
        float sc = (which == 0) ? 0.125f * LOG2E : 1.0f;
#pragma unroll
        for (int r = 0; r < 4; ++r) {
          float val = (acc[mi][ni][r] + bv_) * sc;
          dst[((size_t)(b * NNH + h) * NS + (s0 + r)) * NHD + d] = f2bf(val);
        }
      }
    }
  }
}

// ---------------- kernel 2: flash attention, 8-wave in-block split-KV ----------------
// grid 768 (XCD-remapped), 512 threads = 2 groups x 4 waves. Group g handles
// keys [g*1024,(g+1)*1024); both cover the same 128 q-rows.
// LDS per group: K double-buffer (2x8KB) + V single buffer (8KB) = 24KB
// -> 48KB/block -> 3 blocks/CU co-resident (768 = 3*256: zero tail).
// launch_bounds(512,4): VGPR cap 128, compiler allocates ~64 (proven r7/r8) ->
// residency limited by LDS only = 3 blocks/CU = 6 waves/SIMD. Do NOT raise the
// 2nd arg: (512,6) caps regs at ~85 and spills catastrophically (r6, r9).
__global__ __launch_bounds__(512, 4)
void attn_kernel(const unsigned short* __restrict__ qw,
                 const unsigned short* __restrict__ kw,
                 const unsigned short* __restrict__ vw,
                 const float* __restrict__ mask,
                 float* __restrict__ out) {
  __shared__ unsigned char lds[49152];  // [g][Kbuf0 8K | Kbuf1 8K | V 8K]; reused for merge

  const int tid = threadIdx.x;
  const int lane = tid & 63, wid = tid >> 6;       // wid 0..7
  const int g = wid >> 2, wg = wid & 3;            // group, wave-in-group
  const int l31 = lane & 31, hi = lane >> 5;
  const int r_ = blockIdx.x;           // 0..767
  const int j_ = r_ >> 3, xcd = r_ & 7;
  const int bh = xcd * 6 + (j_ % 6);   // bh-major per XCD
  const int qb = j_ / 6;               // 0..15
  const int b = bh / NNH, h = bh % NNH;
  const size_t bh_off = (size_t)bh * NS * NHD;
  const int qbase = qb * 128 + wg * 32;
  const int qlocal = wg * 32 + l31;    // 0..127 (softmax-domain q within block)

  // hoist Q B-fragments: Q[q = qbase+l31][d = dk*16 + hi*8 + j]
  bf16x8 qf[4];
#pragma unroll
  for (int dk = 0; dk < 4; ++dk)
    qf[dk] = *(const bf16x8*)(qw + bh_off + (size_t)(qbase + l31) * NHD + dk * 16 + hi * 8);

  // staging: per-lane pre-swizzled global offsets (LDS dest is linear)
  const int swz16 = ((lane & 7) * 16) ^ (((lane >> 3) & 7) << 4);
  const unsigned char* kgp = (const unsigned char*)(kw + bh_off);
  const unsigned char* vgp = (const unsigned char*)(vw + bh_off);
  const int kst = (lane >> 3) * 128 + swz16;                 // within K row-block
  const size_t vst = (size_t)(lane >> 3) * (NS * 2) + swz16; // V^T rows stride 4096B

  // ds_read col offsets (swizzled); row&7 == l31&7 for all our reads
  const int swzr = (l31 & 7) << 4;
  int colA[4];
#pragma unroll
  for (int i = 0; i < 4; ++i) colA[i] = (i * 32 + hi * 16) ^ swzr;

  const float* maskp = mask + b * NS + g * 1024;
  unsigned char* const gbase = lds + g * 24576;
  unsigned char* const vbuf = gbase + 16384;

  f32x16 oacc[2];
#pragma unroll
  for (int db = 0; db < 2; ++db)
#pragma unroll
    for (int e = 0; e < 16; ++e) oacc[db][e] = 0.f;
  float mrun = 8.0f;   // static log2-domain exponent bias
  float lrun = 0.f;    // per-lane PARTIAL (own 32 keys); partner-combined at end

#define STAGE_K(t_, buf_) do { \
    size_t kb0 = (size_t)(g * 1024 + (t_) * 64); \
    unsigned char* kd = gbase + (buf_) * 8192; \
    GLDS(kgp + kb0 * 128 + (wg * 2 + 0) * 1024 + kst, kd + (wg * 2 + 0) * 1024); \
    GLDS(kgp + kb0 * 128 + (wg * 2 + 1) * 1024 + kst, kd + (wg * 2 + 1) * 1024); \
  } while (0)
#define STAGE_V(t_) do { \
    size_t kb0 = (size_t)(g * 1024 + (t_) * 64); \
    GLDS(vgp + (size_t)(wg * 2 + 0) * 8 * (NS * 2) + kb0 * 2 + vst, vbuf + (wg * 2 + 0) * 1024); \
    GLDS(vgp + (size_t)(wg * 2 + 1) * 8 * (NS * 2) + kb0 * 2 + vst, vbuf + (wg * 2 + 1) * 1024); \
  } while (0)

  STAGE_K(0, 0);
  __syncthreads();   // K(0) landed + visible

  for (int t = 0; t < 16; ++t) {
    // V(t) overwrite is safe: previous end-of-tile barrier ensured PV(t-1) done.
    STAGE_V(t);
    if (t + 1 < 16) STAGE_K(t + 1, (t + 1) & 1);

    const unsigned char* klds = gbase + (t & 1) * 8192;

    // S^T accumulators, C-init = mask*log2e - mrun (fused: one FMA per element)
    f32x16 acc2[2];
#pragma unroll
    for (int kb = 0; kb < 2; ++kb)
#pragma unroll
      for (int c = 0; c < 4; ++c) {
        float4 mv = *(const float4*)(maskp + t * 64 + kb * 32 + c * 8 + hi * 4);
        acc2[kb][c * 4 + 0] = fmaf(mv.x, LOG2E, -mrun);
        acc2[kb][c * 4 + 1] = fmaf(mv.y, LOG2E, -mrun);
        acc2[kb][c * 4 + 2] = fmaf(mv.z, LOG2E, -mrun);
        acc2[kb][c * 4 + 3] = fmaf(mv.w, LOG2E, -mrun);
      }

    // QK^T (swapped): acc2[kb][reg] = S[q=l31][key = kb*32 + (reg&3)+8*(reg>>2)+4*hi]
    __builtin_amdgcn_s_setprio(1);
#pragma unroll
    for (int kb = 0; kb < 2; ++kb)
#pragma unroll
      for (int dk = 0; dk < 4; ++dk) {
        bf16x8 kf = *(const bf16x8*)(klds + (kb * 32 + l31) * 128 + colA[dk]);
        acc2[kb] = __builtin_amdgcn_mfma_f32_32x32x16_bf16(kf, qf[dk], acc2[kb], 0, 0, 0);
      }
    __builtin_amdgcn_s_setprio(0);

    // p = 2^(S + maskL - mrun) directly (bias already folded into C-init)
#pragma unroll
    for (int kb = 0; kb < 2; ++kb)
#pragma unroll
      for (int e = 0; e < 16; ++e)
        acc2[kb][e] = __builtin_amdgcn_exp2f(acc2[kb][e]);
    float s8[8];
#pragma unroll
    for (int e = 0; e < 8; ++e)
      s8[e] = (acc2[0][e] + acc2[0][e + 8]) + (acc2[1][e] + acc2[1][e + 8]);
    float rsum = ((s8[0] + s8[1]) + (s8[2] + s8[3])) +
                 ((s8[4] + s8[5]) + (s8[6] + s8[7]));

    // cold safety: exact power-of-2 rescale if p's got huge (uniform -> no routing)
    int guard = 0;
    while (!__all(rsum <= 0x1p40f) && ++guard < 4) {
      const float c = 0x1p-64f;
#pragma unroll
      for (int kb = 0; kb < 2; ++kb)
#pragma unroll
        for (int e = 0; e < 16; ++e) acc2[kb][e] *= c;
#pragma unroll
      for (int r = 0; r < 16; ++r) { oacc[0][r] *= c; oacc[1][r] *= c; }
      lrun *= c; rsum *= c; mrun += 64.0f;
    }
    lrun += rsum;

    __syncthreads();   // V(t) (and K(t+1)) drained + visible; staging hid under softmax

    // PV fused per-ks: P->bf16 (cvtpk), partner exchange, MFMA.
    // af[ks][j] = P[q=l31][key = ks*16 + hi*8 + j]
    __builtin_amdgcn_s_setprio(1);
#pragma unroll
    for (int ks = 0; ks < 4; ++ks) {
      const int kb = ks >> 1, cl = (2 * ks) & 3, ch = cl + 1;
      unsigned int wa0 = cvtpk(acc2[kb][cl * 4 + 0], acc2[kb][cl * 4 + 1]);
      unsigned int wa1 = cvtpk(acc2[kb][cl * 4 + 2], acc2[kb][cl * 4 + 3]);
      unsigned int wb0 = cvtpk(acc2[kb][ch * 4 + 0], acc2[kb][ch * 4 + 1]);
      unsigned int wb1 = cvtpk(acc2[kb][ch * 4 + 2], acc2[kb][ch * 4 + 3]);
      unsigned int s0 = hi ? wa0 : wb0;
      unsigned int s1 = hi ? wa1 : wb1;
      unsigned int r0 = __shfl_xor(s0, 32);
      unsigned int r1 = __shfl_xor(s1, 32);
      union { unsigned int u[4]; bf16x8 v; } afu;
      afu.u[0] = hi ? r0 : wa0;
      afu.u[1] = hi ? r1 : wa1;
      afu.u[2] = hi ? wb0 : r0;
      afu.u[3] = hi ? wb1 : r1;
      bf16x8 vf0 = *(const bf16x8*)(vbuf + (0 * 32 + l31) * 128 + colA[ks]);
      bf16x8 vf1 = *(const bf16x8*)(vbuf + (1 * 32 + l31) * 128 + colA[ks]);
      oacc[0] = __builtin_amdgcn_mfma_f32_32x32x16_bf16(afu.v, vf0, oacc[0], 0, 0, 0);
      oacc[1] = __builtin_amdgcn_mfma_f32_32x32x16_bf16(afu.v, vf1, oacc[1], 0, 0, 0);
    }
    __builtin_amdgcn_s_setprio(0);

    __syncthreads();   // PV(t) done by all -> V buffer free for t+1
  }

  // combine partner-lane partial sums once (was per-tile)
  lrun += __shfl_xor(lrun, 32);

  // ---------- two-way flash merge (groups A/B over same q-rows) ----------
  float* fl = (float*)lds;
  // phase 1: publish (m, l) per q; hi==0 lanes write  (post-loop barrier above)
  if (hi == 0) {
    fl[g * 256 + qlocal] = mrun;
    fl[g * 256 + 128 + qlocal] = lrun;
  }
  __syncthreads();
  // phase 2: read other group's stats, compute combined scale
  float mo = fl[(1 - g) * 256 + qlocal];
  float lo_ = fl[(1 - g) * 256 + 128 + qlocal];
  float mstar = fmaxf(mrun, mo);
  float sG = __builtin_amdgcn_exp2f(mrun - mstar);           // own-group scale
  float lstar = lrun * sG + lo_ * __builtin_amdgcn_exp2f(mo - mstar);
  float s_r[16];
#pragma unroll
  for (int r = 0; r < 16; ++r)
    s_r[r] = __shfl(sG, (r & 3) + 8 * (r >> 2) + 4 * hi);
  __syncthreads();                   // stats consumed before O overwrite
  // phase 3: group B writes scaled O to LDS [128 q][64 d] fp32
  if (g == 1) {
#pragma unroll
    for (int reg = 0; reg < 16; ++reg) {
      int qr = wg * 32 + (reg & 3) + 8 * (reg >> 2) + 4 * hi;
      fl[qr * 64 + l31]      = oacc[0][reg] * s_r[reg];
      fl[qr * 64 + 32 + l31] = oacc[1][reg] * s_r[reg];
    }
  }
  __syncthreads();
  // phase 4: group A combines, normalizes, stores fp32 merge-heads layout
  if (g == 0) {
    float invl = 1.0f / lstar;       // softmax domain (q = l31)
#pragma unroll
    for (int reg = 0; reg < 16; ++reg) {
      int q_local = (reg & 3) + 8 * (reg >> 2) + 4 * hi;
      float inv_r = __shfl(invl, q_local);
      int qr = wg * 32 + q_local;
      int q = qb * 128 + qr;
      float o0 = oacc[0][reg] * s_r[reg] + fl[qr * 64 + l31];
      float o1 = oacc[1][reg] * s_r[reg] + fl[qr * 64 + 32 + l31];
      out[((size_t)b * NS + q) * NHID + h * 64 + l31]      = o0 * inv_r;
      out[((size_t)b * NS + q) * NHID + h * 64 + 32 + l31] = o1 * inv_r;
    }
  }
#undef STAGE_K
#undef STAGE_V
}

extern "C" void kernel_launch(void* const* d_in, const int* in_sizes, int n_in,
                              void* d_out, int out_size, void* d_ws, size_t ws_size,
                              hipStream_t stream) {
  const float* X    = (const float*)d_in[0];
  const float* mask = (const float*)d_in[1];
  const float* Wq   = (const float*)d_in[2];
  const float* bq   = (const float*)d_in[3];
  const float* Wk   = (const float*)d_in[4];
  const float* bk   = (const float*)d_in[5];
  const float* Wv   = (const float*)d_in[6];
  const float* bv   = (const float*)d_in[7];
  float* out = (float*)d_out;

  unsigned short* xb = (unsigned short*)d_out;            // scratch, overwritten by attn out
  unsigned short* wb = xb + (size_t)NB * NS * NHID;
  unsigned short* qw = (unsigned short*)d_ws;
  unsigned short* kw = qw + (size_t)NBH * NS * NHD;
  unsigned short* vw = kw + (size_t)NBH * NS * NHD;

  cvt_kernel<<<7872, 256, 0, stream>>>(X, Wq, Wk, Wv, xb, wb);
  qkv_gemm<<<dim3(64, 18), 256, 0, stream>>>(xb, wb, bq, bk, bv, qw, kw, vw);
  attn_kernel<<<768, 512, 0, stream>>>(qw, kw, vw, mask, out);
}

// Round 11
// 127.553 us; speedup vs baseline: 2.9413x; 1.0353x over previous
//
#include <hip/hip_runtime.h>
#include <stdint.h>

#define NB 4
#define NS 2048
#define NHID 768
#define NNH 12
#define NHD 64
#define NBH 48
#define LOG2E 1.4426950408889634f

typedef __attribute__((ext_vector_type(8))) __bf16 bf16x8;
typedef __attribute__((ext_vector_type(4))) float f32x4;
typedef __attribute__((ext_vector_type(16))) float f32x16;

static __device__ __forceinline__ unsigned short f2bf(float f) {
  union { float f; uint32_t u; } v; v.f = f;
  uint32_t r = (v.u + 0x7FFFu + ((v.u >> 16) & 1u)) >> 16;  // RNE
  return (unsigned short)r;
}

static __device__ __forceinline__ unsigned int cvtpk(float lo, float hi) {
  unsigned int r;
  asm("v_cvt_pk_bf16_f32 %0, %1, %2" : "=v"(r) : "v"(lo), "v"(hi));
  return r;
}

#define GLDS(src, dst) __builtin_amdgcn_global_load_lds( \
    (const __attribute__((address_space(1))) void*)(src), \
    (__attribute__((address_space(3))) void*)(dst), 16, 0, 0)

// ---------------- kernel 0: fp32 -> bf16 (X and W concat) ----------------
__global__ void cvt_kernel(const float* __restrict__ X,
                           const float* __restrict__ Wq,
                           const float* __restrict__ Wk,
                           const float* __restrict__ Wv,
                           unsigned short* __restrict__ xb,
                           unsigned short* __restrict__ wb) {
  const int NX = NB * NS * NHID;   // 6291456
  const int NW = NHID * NHID;      // 589824
  int i = (blockIdx.x * blockDim.x + threadIdx.x) * 4;
  if (i < NX) {
    const float4 v = *(const float4*)(X + i);
    ushort4 o;
    o.x = f2bf(v.x); o.y = f2bf(v.y); o.z = f2bf(v.z); o.w = f2bf(v.w);
    *(ushort4*)(xb + i) = o;
  } else {
    int j = i - NX;
    const float* W; int jj;
    if (j < NW)          { W = Wq; jj = j; }
    else if (j < 2 * NW) { W = Wk; jj = j - NW; }
    else                 { W = Wv; jj = j - 2 * NW; }
    const float4 v = *(const float4*)(W + jj);
    ushort4 o;
    o.x = f2bf(v.x); o.y = f2bf(v.y); o.z = f2bf(v.z); o.w = f2bf(v.w);
    *(ushort4*)(wb + j) = o;
  }
}

// ---------------- kernel 1: fused QKV projection GEMM ----------------
// 128x128 tile, BK=64, 4 waves, global_load_lds(16B) into XOR-swizzled LDS.
__global__ void qkv_gemm(const unsigned short* __restrict__ xb,   // [8192][768] bf16
                         const unsigned short* __restrict__ wb,   // [3][768][768] bf16
                         const float* __restrict__ bq,
                         const float* __restrict__ bk,
                         const float* __restrict__ bv,
                         unsigned short* __restrict__ qw,   // [48][2048][64] (scaled 0.125*log2e)
                         unsigned short* __restrict__ kw,   // [48][2048][64]
                         unsigned short* __restrict__ vw) { // [48][64][2048] (transposed)
  __shared__ unsigned char As[128 * 128];   // [row][128B K-slab], swizzled
  __shared__ unsigned char Bs[128 * 128];
  const int tid = threadIdx.x;
  const int lane = tid & 63, wid = tid >> 6;
  const int l15 = lane & 15, l4 = lane >> 4;
  const int wr = wid >> 1, wc = wid & 1;
  const int mblock = blockIdx.x;   // 0..63
  const int ct = blockIdx.y;       // 0..17
  const int which = ct / 6, ctn = ct % 6;
  const int mbase = mblock * 128, nbase = ctn * 128;
  const unsigned short* Wb = wb + (size_t)which * NHID * NHID;

  const int srow = lane >> 3;                               // 0..7
  const int swz16 = ((lane & 7) * 16) ^ (srow << 4);        // < 128
  const unsigned char* agp = (const unsigned char*)xb + (size_t)mbase * (NHID * 2);
  const unsigned char* bgp = (const unsigned char*)Wb + (size_t)nbase * (NHID * 2);

  f32x4 acc[4][4];
  const f32x4 fzero = {0.f, 0.f, 0.f, 0.f};
#pragma unroll
  for (int mi = 0; mi < 4; ++mi)
#pragma unroll
    for (int ni = 0; ni < 4; ++ni) acc[mi][ni] = fzero;

  const int swzr = (l15 & 7) << 4;   // read-side XOR (row&7 == l15&7)

  for (int kt = 0; kt < 12; ++kt) {
    __syncthreads();
#pragma unroll
    for (int g = 0; g < 4; ++g) {
      int row = wid * 32 + g * 8 + srow;
      GLDS(agp + (size_t)row * (NHID * 2) + kt * 128 + swz16,
           As + (wid * 32 + g * 8) * 128);
      GLDS(bgp + (size_t)row * (NHID * 2) + kt * 128 + swz16,
           Bs + (wid * 32 + g * 8) * 128);
    }
    __syncthreads();   // vmcnt drained by barrier
#pragma unroll
    for (int ks = 0; ks < 2; ++ks) {
      bf16x8 af[4], bf[4];
#pragma unroll
      for (int mi = 0; mi < 4; ++mi)
        af[mi] = *(const bf16x8*)(As + (wr * 64 + mi * 16 + l15) * 128 +
                                  ((ks * 64 + l4 * 16) ^ swzr));
#pragma unroll
      for (int ni = 0; ni < 4; ++ni)
        bf[ni] = *(const bf16x8*)(Bs + (wc * 64 + ni * 16 + l15) * 128 +
                                  ((ks * 64 + l4 * 16) ^ swzr));
#pragma unroll
      for (int mi = 0; mi < 4; ++mi)
#pragma unroll
        for (int ni = 0; ni < 4; ++ni)
          acc[mi][ni] = __builtin_amdgcn_mfma_f32_16x16x32_bf16(af[mi], bf[ni], acc[mi][ni], 0, 0, 0);
    }
  }

  const float* bias = (which == 0) ? bq : (which == 1) ? bk : bv;
#pragma unroll
  for (int mi = 0; mi < 4; ++mi) {
    int row0 = mbase + wr * 64 + mi * 16 + l4 * 4;
    int b = row0 >> 11, s0 = row0 & 2047;
#pragma unroll
    for (int ni = 0; ni < 4; ++ni) {
      int col = nbase + wc * 64 + ni * 16 + l15;   // 0..767
      float bv_ = bias[col];
      int h = col >> 6, d = col & 63;
      if (which == 2) {
        ushort4 o;
        o.x = f2bf(acc[mi][ni][0] + bv_);
        o.y = f2bf(acc[mi][ni][1] + bv_);
        o.z = f2bf(acc[mi][ni][2] + bv_);
        o.w = f2bf(acc[mi][ni][3] + bv_);
        *(ushort4*)(vw + ((size_t)(b * NNH + h) * NHD + d) * NS + s0) = o;
      } else {
        unsigned short* dst = (which == 0) ? qw : kw;
        // Q carries 1/sqrt(64) * log2e so scores come out in log2 units
        float sc = (which == 0) ? 0.125f * LOG2E : 1.0f;
#pragma unroll
        for (int r = 0; r < 4; ++r) {
          float val = (acc[mi][ni][r] + bv_) * sc;
          dst[((size_t)(b * NNH + h) * NS + (s0 + r)) * NHD + d] = f2bf(val);
        }
      }
    }
  }
}

// ---------------- kernel 2: flash attention, 8-wave in-block split-KV ----------------
// grid 768 (XCD-remapped), 512 threads = 2 groups x 4 waves. Group g handles
// keys [g*1024,(g+1)*1024); both cover the same 128 q-rows.
// Both K and V double-buffered and staged ONE TILE AHEAD -> a single barrier
// per tile (staging latency gets a full tile of cover; no mid-tile drain).
// C-init comes from an LDS-precomputed cmask[key] = mask*log2e - 8 (8KB),
// removing per-tile global loads + 32 fmaf from the loop.
// LDS: per group K dbuf 16KB + V dbuf 16KB = 64KB + cmask 8KB = 72KB.
// launch_bounds(512,4): VGPR cap 128, compiler uses ~64 (r7/r8/r10 proven,
// zero spill). Do NOT raise 2nd arg: (512,6) spills catastrophically (r6,r9).
__global__ __launch_bounds__(512, 4)
void attn_kernel(const unsigned short* __restrict__ qw,
                 const unsigned short* __restrict__ kw,
                 const unsigned short* __restrict__ vw,
                 const float* __restrict__ mask,
                 float* __restrict__ out) {
  __shared__ unsigned char lds[73728];

  const int tid = threadIdx.x;
  const int lane = tid & 63, wid = tid >> 6;       // wid 0..7
  const int g = wid >> 2, wg = wid & 3;            // group, wave-in-group
  const int l31 = lane & 31, hi = lane >> 5;
  const int r_ = blockIdx.x;           // 0..767
  const int j_ = r_ >> 3, xcd = r_ & 7;
  const int bh = xcd * 6 + (j_ % 6);   // bh-major per XCD
  const int qb = j_ / 6;               // 0..15
  const int b = bh / NNH, h = bh % NNH;
  const size_t bh_off = (size_t)bh * NS * NHD;
  const int qbase = qb * 128 + wg * 32;
  const int qlocal = wg * 32 + l31;    // 0..127 (softmax-domain q within block)

  unsigned char* const gbase = lds + g * 32768;    // [K0|K1|V0|V1] x 8KB
  float* const cmask = (float*)(lds + 65536);      // [2048] indexed by global key

  // precompute C-init values: cmask[key] = mask[b][key]*log2e - 8 (static bias)
  {
    const float4 mv = *(const float4*)(mask + (size_t)b * NS + tid * 4);
    float4 cv;
    cv.x = fmaf(mv.x, LOG2E, -8.0f);
    cv.y = fmaf(mv.y, LOG2E, -8.0f);
    cv.z = fmaf(mv.z, LOG2E, -8.0f);
    cv.w = fmaf(mv.w, LOG2E, -8.0f);
    *(float4*)(cmask + tid * 4) = cv;
  }

  // hoist Q B-fragments: Q[q = qbase+l31][d = dk*16 + hi*8 + j]
  bf16x8 qf[4];
#pragma unroll
  for (int dk = 0; dk < 4; ++dk)
    qf[dk] = *(const bf16x8*)(qw + bh_off + (size_t)(qbase + l31) * NHD + dk * 16 + hi * 8);

  // staging: per-lane pre-swizzled global offsets (LDS dest is linear)
  const int swz16 = ((lane & 7) * 16) ^ (((lane >> 3) & 7) << 4);
  const unsigned char* kgp = (const unsigned char*)(kw + bh_off);
  const unsigned char* vgp = (const unsigned char*)(vw + bh_off);
  const int kst = (lane >> 3) * 128 + swz16;                 // within K row-block
  const size_t vst = (size_t)(lane >> 3) * (NS * 2) + swz16; // V^T rows stride 4096B

  // ds_read col offsets (swizzled); row&7 == l31&7 for all our reads
  const int swzr = (l31 & 7) << 4;
  int colA[4];
#pragma unroll
  for (int i = 0; i < 4; ++i) colA[i] = (i * 32 + hi * 16) ^ swzr;

  f32x16 oacc[2];
#pragma unroll
  for (int db = 0; db < 2; ++db)
#pragma unroll
    for (int e = 0; e < 16; ++e) oacc[db][e] = 0.f;
  float mrun = 8.0f;   // static log2-domain exponent bias
  float lrun = 0.f;    // per-lane PARTIAL (own 32 keys); partner-combined at end

#define STAGE_K(t_) do { \
    size_t kk = (size_t)(g * 1024 + (t_) * 64); \
    unsigned char* kd = gbase + ((t_) & 1) * 8192; \
    GLDS(kgp + kk * 128 + (wg * 2 + 0) * 1024 + kst, kd + (wg * 2 + 0) * 1024); \
    GLDS(kgp + kk * 128 + (wg * 2 + 1) * 1024 + kst, kd + (wg * 2 + 1) * 1024); \
  } while (0)
#define STAGE_V(t_) do { \
    size_t kk = (size_t)(g * 1024 + (t_) * 64); \
    unsigned char* vd = gbase + 16384 + ((t_) & 1) * 8192; \
    GLDS(vgp + (size_t)(wg * 2 + 0) * 8 * (NS * 2) + kk * 2 + vst, vd + (wg * 2 + 0) * 1024); \
    GLDS(vgp + (size_t)(wg * 2 + 1) * 8 * (NS * 2) + kk * 2 + vst, vd + (wg * 2 + 1) * 1024); \
  } while (0)

  STAGE_K(0);
  STAGE_V(0);
  __syncthreads();   // cmask + K(0) + V(0) visible

  for (int t = 0; t < 16; ++t) {
    // stage t+1 into the buffers freed at the previous barrier
    if (t + 1 < 16) { STAGE_K(t + 1); STAGE_V(t + 1); }

    const unsigned char* klds = gbase + (t & 1) * 8192;
    const unsigned char* vlds = gbase + 16384 + (t & 1) * 8192;
    const float* cmt = cmask + g * 1024 + t * 64;

    // S^T accumulators, C-init from LDS (broadcast reads, bias pre-folded)
    f32x16 acc2[2];
#pragma unroll
    for (int kb = 0; kb < 2; ++kb)
#pragma unroll
      for (int c = 0; c < 4; ++c) {
        float4 cv = *(const float4*)(cmt + kb * 32 + c * 8 + hi * 4);
        acc2[kb][c * 4 + 0] = cv.x;
        acc2[kb][c * 4 + 1] = cv.y;
        acc2[kb][c * 4 + 2] = cv.z;
        acc2[kb][c * 4 + 3] = cv.w;
      }

    // QK^T (swapped): acc2[kb][reg] = S[q=l31][key = kb*32 + (reg&3)+8*(reg>>2)+4*hi]
    __builtin_amdgcn_s_setprio(1);
#pragma unroll
    for (int kb = 0; kb < 2; ++kb)
#pragma unroll
      for (int dk = 0; dk < 4; ++dk) {
        bf16x8 kf = *(const bf16x8*)(klds + (kb * 32 + l31) * 128 + colA[dk]);
        acc2[kb] = __builtin_amdgcn_mfma_f32_32x32x16_bf16(kf, qf[dk], acc2[kb], 0, 0, 0);
      }
    __builtin_amdgcn_s_setprio(0);

    // bias correction (cmask bakes -8; only relevant if the cold guard ever fired)
    if (mrun != 8.0f) {
      float corr = mrun - 8.0f;
#pragma unroll
      for (int kb = 0; kb < 2; ++kb)
#pragma unroll
        for (int e = 0; e < 16; ++e) acc2[kb][e] -= corr;
    }

    // p = 2^(S + maskL - mrun) directly
#pragma unroll
    for (int kb = 0; kb < 2; ++kb)
#pragma unroll
      for (int e = 0; e < 16; ++e)
        acc2[kb][e] = __builtin_amdgcn_exp2f(acc2[kb][e]);
    float s8[8];
#pragma unroll
    for (int e = 0; e < 8; ++e)
      s8[e] = (acc2[0][e] + acc2[0][e + 8]) + (acc2[1][e] + acc2[1][e + 8]);
    float rsum = ((s8[0] + s8[1]) + (s8[2] + s8[3])) +
                 ((s8[4] + s8[5]) + (s8[6] + s8[7]));

    // cold safety: exact power-of-2 rescale if p's got huge (uniform -> no routing)
    int guard = 0;
    while (!__all(rsum <= 0x1p40f) && ++guard < 4) {
      const float c = 0x1p-64f;
#pragma unroll
      for (int kb = 0; kb < 2; ++kb)
#pragma unroll
        for (int e = 0; e < 16; ++e) acc2[kb][e] *= c;
#pragma unroll
      for (int r = 0; r < 16; ++r) { oacc[0][r] *= c; oacc[1][r] *= c; }
      lrun *= c; rsum *= c; mrun += 64.0f;
    }
    lrun += rsum;

    // PV fused per-ks: P->bf16 (cvtpk), partner exchange, MFMA.
    // af[ks][j] = P[q=l31][key = ks*16 + hi*8 + j]
    __builtin_amdgcn_s_setprio(1);
#pragma unroll
    for (int ks = 0; ks < 4; ++ks) {
      const int kb = ks >> 1, cl = (2 * ks) & 3, ch = cl + 1;
      unsigned int wa0 = cvtpk(acc2[kb][cl * 4 + 0], acc2[kb][cl * 4 + 1]);
      unsigned int wa1 = cvtpk(acc2[kb][cl * 4 + 2], acc2[kb][cl * 4 + 3]);
      unsigned int wb0 = cvtpk(acc2[kb][ch * 4 + 0], acc2[kb][ch * 4 + 1]);
      unsigned int wb1 = cvtpk(acc2[kb][ch * 4 + 2], acc2[kb][ch * 4 + 3]);
      unsigned int s0 = hi ? wa0 : wb0;
      unsigned int s1 = hi ? wa1 : wb1;
      unsigned int r0 = __shfl_xor(s0, 32);
      unsigned int r1 = __shfl_xor(s1, 32);
      union { unsigned int u[4]; bf16x8 v; } afu;
      afu.u[0] = hi ? r0 : wa0;
      afu.u[1] = hi ? r1 : wa1;
      afu.u[2] = hi ? wb0 : r0;
      afu.u[3] = hi ? wb1 : r1;
      bf16x8 vf0 = *(const bf16x8*)(vlds + (0 * 32 + l31) * 128 + colA[ks]);
      bf16x8 vf1 = *(const bf16x8*)(vlds + (1 * 32 + l31) * 128 + colA[ks]);
      oacc[0] = __builtin_amdgcn_mfma_f32_32x32x16_bf16(afu.v, vf0, oacc[0], 0, 0, 0);
      oacc[1] = __builtin_amdgcn_mfma_f32_32x32x16_bf16(afu.v, vf1, oacc[1], 0, 0, 0);
    }
    __builtin_amdgcn_s_setprio(0);

    // single barrier per tile: drains vmcnt (t+1 staged+visible) and frees
    // this tile's K/V buffers for the t+1 iteration's staging of t+2.
    __syncthreads();
  }

  // combine partner-lane partial sums once (was per-tile)
  lrun += __shfl_xor(lrun, 32);

  // ---------- two-way flash merge (groups A/B over same q-rows) ----------
  float* fl = (float*)lds;
  // phase 1: publish (m, l) per q; hi==0 lanes write  (post-loop barrier above)
  if (hi == 0) {
    fl[g * 256 + qlocal] = mrun;
    fl[g * 256 + 128 + qlocal] = lrun;
  }
  __syncthreads();
  // phase 2: read other group's stats, compute combined scale
  float mo = fl[(1 - g) * 256 + qlocal];
  float lo_ = fl[(1 - g) * 256 + 128 + qlocal];
  float mstar = fmaxf(mrun, mo);
  float sG = __builtin_amdgcn_exp2f(mrun - mstar);           // own-group scale
  float lstar = lrun * sG + lo_ * __builtin_amdgcn_exp2f(mo - mstar);
  float s_r[16];
#pragma unroll
  for (int r = 0; r < 16; ++r)
    s_r[r] = __shfl(sG, (r & 3) + 8 * (r >> 2) + 4 * hi);
  __syncthreads();                   // stats consumed before O overwrite
  // phase 3: group B writes scaled O to LDS [128 q][64 d] fp32
  if (g == 1) {
#pragma unroll
    for (int reg = 0; reg < 16; ++reg) {
      int qr = wg * 32 + (reg & 3) + 8 * (reg >> 2) + 4 * hi;
      fl[qr * 64 + l31]      = oacc[0][reg] * s_r[reg];
      fl[qr * 64 + 32 + l31] = oacc[1][reg] * s_r[reg];
    }
  }
  __syncthreads();
  // phase 4: group A combines, normalizes, stores fp32 merge-heads layout
  if (g == 0) {
    float invl = 1.0f / lstar;       // softmax domain (q = l31)
#pragma unroll
    for (int reg = 0; reg < 16; ++reg) {
      int q_local = (reg & 3) + 8 * (reg >> 2) + 4 * hi;
      float inv_r = __shfl(invl, q_local);
      int qr = wg * 32 + q_local;
      int q = qb * 128 + qr;
      float o0 = oacc[0][reg] * s_r[reg] + fl[qr * 64 + l31];
      float o1 = oacc[1][reg] * s_r[reg] + fl[qr * 64 + 32 + l31];
      out[((size_t)b * NS + q) * NHID + h * 64 + l31]      = o0 * inv_r;
      out[((size_t)b * NS + q) * NHID + h * 64 + 32 + l31] = o1 * inv_r;
    }
  }
#undef STAGE_K
#undef STAGE_V
}

extern "C" void kernel_launch(void* const* d_in, const int* in_sizes, int n_in,
                              void* d_out, int out_size, void* d_ws, size_t ws_size,
                              hipStream_t stream) {
  const float* X    = (const float*)d_in[0];
  const float* mask = (const float*)d_in[1];
  const float* Wq   = (const float*)d_in[2];
  const float* bq   = (const float*)d_in[3];
  const float* Wk   = (const float*)d_in[4];
  const float* bk   = (const float*)d_in[5];
  const float* Wv   = (const float*)d_in[6];
  const float* bv   = (const float*)d_in[7];
  float* out = (float*)d_out;

  unsigned short* xb = (unsigned short*)d_out;            // scratch, overwritten by attn out
  unsigned short* wb = xb + (size_t)NB * NS * NHID;
  unsigned short* qw = (unsigned short*)d_ws;
  unsigned short* kw = qw + (size_t)NBH * NS * NHD;
  unsigned short* vw = kw + (size_t)NBH * NS * NHD;

  cvt_kernel<<<7872, 256, 0, stream>>>(X, Wq, Wk, Wv, xb, wb);
  qkv_gemm<<<dim3(64, 18), 256, 0, stream>>>(xb, wb, bq, bk, bv, qw, kw, vw);
  attn_kernel<<<768, 512, 0, stream>>>(qw, kw, vw, mask, out);
}